// Round 4
// baseline (91428.186 us; speedup 1.0000x reference)
//
#include <hip/hip_runtime.h>
#include <stdint.h>

#define T_ 1024
#define B_ 128
#define IN_ 100
#define H_ 200

typedef unsigned short u16;

__device__ __forceinline__ float bf2f(u16 u) {
    union { uint32_t i; float f; } v; v.i = ((uint32_t)u) << 16; return v.f;
}
__device__ __forceinline__ u16 f2bf(float f) {
    union { uint32_t i; float f; } v; v.f = f;
    uint32_t x = v.i;
    x += 0x7fff + ((x >> 16) & 1);   // round-to-nearest-even
    return (u16)(x >> 16);
}

// relaxed spin; caller issues __threadfence() afterwards for acquire.
__device__ __forceinline__ void spin_ge(int* p, int val, int* budget) {
    while (__hip_atomic_load(p, __ATOMIC_RELAXED, __HIP_MEMORY_SCOPE_AGENT) < val) {
        __builtin_amdgcn_s_sleep(1);
        if (--(*budget) < 0) return;   // hang safety -> finite garbage, not hang
    }
}

// ---------- dtype detector: are the raw inputs f32 or bf16? ----------
// Genuine bf16 weights: every u16 has exponent<0xFF and |value|<=~0.08 -> bad==0.
// f32 weights read as u16: even indices are float low-halves = random bits ->
// ~half exceed 0.5 or hit exponent 0xFF -> bad ~ 1000.  Threshold 64.
__global__ void detect_kernel(const void* w, int* flag) {
    __shared__ int cnt;
    if (threadIdx.x == 0) cnt = 0;
    __syncthreads();
    const u16* p = (const u16*)w;
    int bad = 0;
    for (int e = 0; e < 16; ++e) {
        u16 u = p[threadIdx.x * 16 + e];
        int ex = (u >> 7) & 0xFF;
        float v = bf2f(u);
        float av = v < 0.f ? -v : v;
        if (ex == 0xFF || av > 0.5f) bad++;
    }
    atomicAdd(&cnt, bad);
    __syncthreads();
    if (threadIdx.x == 0) flag[0] = (cnt > 64) ? 1 : 0;
}

// ---------- canonicalize params: weights/biases/fc -> bf16, h0/c0 -> f32 ----
// canonical u16 layout (element offsets):
//   Wih0@0[80000] Whh0@80000[160000] bih0@240000[800] bhh0@240800[800]
//   Wih1@241600[160000] Whh1@401600[160000] bih1@561600[800] bhh1@562400[800]
//   fcW@563200[20000] fcb@583200[100]          (total 583300)
__global__ void prep_kernel(const void* Wih0, const void* Whh0,
                            const void* bih0, const void* bhh0,
                            const void* Wih1, const void* Whh1,
                            const void* bih1, const void* bhh1,
                            const void* fcW,  const void* fcb,
                            const void* h0,   const void* c0,
                            u16* cbf, float* ch0, float* cc0, const int* flag)
{
    const int isf32 = *flag;
    const int N = 685700;
    for (int idx = blockIdx.x * 256 + threadIdx.x; idx < N; idx += gridDim.x * 256) {
        const void* src; int e = idx; u16* du = nullptr; float* df = nullptr;
        if (e < 80000)                 { src = Wih0; du = cbf; }
        else if ((e -= 80000) < 160000){ src = Whh0; du = cbf + 80000; }
        else if ((e -= 160000) < 800)  { src = bih0; du = cbf + 240000; }
        else if ((e -= 800) < 800)     { src = bhh0; du = cbf + 240800; }
        else if ((e -= 800) < 160000)  { src = Wih1; du = cbf + 241600; }
        else if ((e -= 160000) < 160000){ src = Whh1; du = cbf + 401600; }
        else if ((e -= 160000) < 800)  { src = bih1; du = cbf + 561600; }
        else if ((e -= 800) < 800)     { src = bhh1; du = cbf + 562400; }
        else if ((e -= 800) < 20000)   { src = fcW;  du = cbf + 563200; }
        else if ((e -= 20000) < 100)   { src = fcb;  du = cbf + 583200; }
        else if ((e -= 100) < 51200)   { src = h0;   df = ch0; }
        else         { e -= 51200;       src = c0;   df = cc0; }
        float v = isf32 ? ((const float*)src)[e] : bf2f(((const u16*)src)[e]);
        if (du) du[e] = f2bf(v); else df[e] = v;
    }
}

// 512 blocks x 256 threads, 2 blocks/CU (LDS 57.6KB), all co-resident.
// Decomposition: role (4) x j (8 col-slices of 25) x i (16 batch-slices of 8).
//   role0: L0 x-half  role1: L0 h-half+cell  role2: L1 x-half  role3: L1 h-half+cell
// x-halves run ahead through depth-8 rings; h-halves carry the recurrence.
__launch_bounds__(256, 2)
__global__ void lstm_pipe(const void* __restrict__ inp,
                          const u16* __restrict__ cbf,
                          const float* __restrict__ ch0, const float* __restrict__ cc0,
                          u16* y1buf, u16* y0ring, float* pr0, float* pr1,
                          float* hbuf0, float* hbuf1,
                          int* f0x, int* f1x, int* cnt0h, int* cnt1x, int* cnt1h,
                          const int* __restrict__ flag, void* __restrict__ out)
{
    __shared__ __align__(16) float smem[14400];   // 57,600 B

    const int isf32 = *flag;
    const int tid = threadIdx.x;
    const int bid = blockIdx.x;
    const int q   = bid >> 3;
    const int role= q & 3;
    const int r2  = q >> 2;
    const int ih  = r2 & 1;
    const int j   = r2 >> 1;                // 0..7  (25-col slice)
    const int i   = (ih << 3) | (bid & 7);  // 0..15 (8-row batch slice)
    const int b0  = i * 8;
    const int hc0 = j * 25;
    const int Kx  = (role == 0) ? 100 : 200;

    // LDS layout (floats)
    u16* Wb = (u16*)smem;                   // [Kx][100] bf16, k-major
    float *xh, *part, *bias = nullptr, *gates = nullptr;
    if (role == 0) { xh = smem + 5000;  part = smem + 6000;  bias = smem + 7600; }
    else           { xh = smem + 10000; part = smem + 12000;
                     if (role == 2) bias = smem + 13600; else gates = smem + 13600; }

    // ---- load canonical weight slice (bf16, k-major) + bias ----
    {
        const u16* Wsrc = (role == 0) ? cbf : (role == 1) ? cbf + 80000
                        : (role == 2) ? cbf + 241600 : cbf + 401600;
        const int ldw = (role == 0) ? IN_ : H_;
        for (int idx = tid; idx < Kx * 100; idx += 256) {
            int k = idx / 100, r = idx % 100;
            int R = (r / 25) * 200 + hc0 + (r % 25);   // r = gate*25 + col
            Wb[k * 100 + r] = Wsrc[R * ldw + k];
        }
        if ((role == 0 || role == 2) && tid < 100) {
            int R = (tid / 25) * 200 + hc0 + (tid % 25);
            bias[tid] = (role == 0) ? (bf2f(cbf[240000 + R]) + bf2f(cbf[240800 + R]))
                                    : (bf2f(cbf[561600 + R]) + bf2f(cbf[562400 + R]));
        }
    }
    float cReg = 0.f;                       // c-state register (h-half roles)
    if ((role == 1 || role == 3) && tid < 200) {
        int b = tid / 25, hc = tid % 25;
        cReg = cc0[((role == 3) ? 1 : 0) * B_ * H_ + (b0 + b) * H_ + hc0 + hc];
    }
    __syncthreads();

    // GEMM mapping: w<25 -> 4 cols, bg -> 2 batch rows, kp -> K/2 chunk
    const int w  = tid & 31;
    const int qq = tid >> 5;
    const int bg = qq & 3;
    const int kp = qq >> 2;
    const int r4 = w * 4;
    const int chunk = Kx / 2;               // 50 or 100

    int budget = 2000000;

    for (int t = 0; t < T_; ++t) {
        // ---- dependency + ring-space spins ----
        if (role == 0) {
            if (t >= 8) spin_ge(cnt0h + (t - 8) * 16 + i, 8, &budget);
        } else if (role == 1) {
            spin_ge(f0x + (t * 16 + i) * 8 + j, 1, &budget);
            if (t > 0)  spin_ge(cnt0h + (t - 1) * 16 + i, 8, &budget);
            if (t >= 8) spin_ge(cnt1x + (t - 8) * 16 + i, 8, &budget);
        } else if (role == 2) {
            spin_ge(cnt0h + t * 16 + i, 8, &budget);
            if (t >= 8) spin_ge(cnt1h + (t - 8) * 16 + i, 8, &budget);
        } else {
            spin_ge(f1x + (t * 16 + i) * 8 + j, 1, &budget);
            if (t > 0) spin_ge(cnt1h + (t - 1) * 16 + i, 8, &budget);
        }
        __threadfence();                    // acquire
        __syncthreads();

        // ---- stage x or h into LDS: xh[k*10 + b], f32 ----
        if (role == 0) {
            for (int idx = tid; idx < 800; idx += 256) {
                int k = idx % 100, b = idx / 100;
                const size_t gi = (size_t)(t * B_ + b0 + b) * IN_ + k;
                xh[k * 10 + b] = isf32 ? ((const float*)inp)[gi]
                                       : bf2f(((const u16*)inp)[gi]);
            }
        } else if (role == 1) {
            for (int idx = tid; idx < 1600; idx += 256) {
                int k = idx % 200, b = idx / 200;
                xh[k * 10 + b] = (t == 0) ? ch0[(b0 + b) * H_ + k]
                    : hbuf0[((t - 1) & 1) * B_ * H_ + (b0 + b) * H_ + k];
            }
        } else if (role == 2) {
            for (int idx = tid; idx < 1600; idx += 256) {
                int k = idx % 200, b = idx / 200;
                xh[k * 10 + b] = bf2f(y0ring[((t & 7) * B_ + b0 + b) * H_ + k]);
            }
        } else {
            for (int idx = tid; idx < 1600; idx += 256) {
                int k = idx % 200, b = idx / 200;
                xh[k * 10 + b] = (t == 0) ? ch0[B_ * H_ + (b0 + b) * H_ + k]
                    : hbuf1[((t - 1) & 1) * B_ * H_ + (b0 + b) * H_ + k];
            }
        }
        __syncthreads();

        // ---- GEMM: 4 cols x 2 batch rows x K/2 per thread ----
        if (w < 25) {
            float4 aA = {0,0,0,0}, aB = {0,0,0,0};
            const u16*   wp = Wb + kp * chunk * 100 + r4;
            const float* xp = xh + kp * chunk * 10 + 2 * bg;
            for (int kk = 0; kk < chunk; ++kk) {
                const ushort4 wu = *(const ushort4*)wp;
                const float w0 = bf2f(wu.x), w1 = bf2f(wu.y),
                            w2 = bf2f(wu.z), w3 = bf2f(wu.w);
                const float x0 = xp[0], x1 = xp[1];
                aA.x = fmaf(w0, x0, aA.x); aA.y = fmaf(w1, x0, aA.y);
                aA.z = fmaf(w2, x0, aA.z); aA.w = fmaf(w3, x0, aA.w);
                aB.x = fmaf(w0, x1, aB.x); aB.y = fmaf(w1, x1, aB.y);
                aB.z = fmaf(w2, x1, aB.z); aB.w = fmaf(w3, x1, aB.w);
                wp += 100; xp += 10;
            }
            float* pp = part + ((kp * 4 + bg) * 25 + w) * 8;
            *(float4*)pp       = aA;
            *(float4*)(pp + 4) = aB;
        }
        __syncthreads();

        // ---- reduce k-chunks; x-halves emit partials, h-halves form gates ----
        if (tid < 200) {
            int b = tid / 25, w2 = tid % 25, bgr = b >> 1, bsr = b & 1;
            const float4 p0 = *(const float4*)(part + ((0 + bgr) * 25 + w2) * 8 + bsr * 4);
            const float4 p1 = *(const float4*)(part + ((4 + bgr) * 25 + w2) * 8 + bsr * 4);
            float4 s = { p0.x + p1.x, p0.y + p1.y, p0.z + p1.z, p0.w + p1.w };
            const int r4r = w2 * 4;
            const size_t roff = ((size_t)(t & 7) * B_ + b0 + b) * 800 + j * 100 + r4r;
            if (role == 0 || role == 2) {
                const float4 bv = *(const float4*)(bias + r4r);
                float* ring = ((role == 0) ? pr0 : pr1) + roff;
                ring[0] = s.x + bv.x; ring[1] = s.y + bv.y;
                ring[2] = s.z + bv.z; ring[3] = s.w + bv.w;
            } else {
                const float* ring = ((role == 1) ? pr0 : pr1) + roff;
                float* gp = gates + b * 100 + r4r;
                gp[0] = s.x + ring[0]; gp[1] = s.y + ring[1];
                gp[2] = s.z + ring[2]; gp[3] = s.w + ring[3];
            }
        }
        __threadfence();
        __syncthreads();

        if (role == 0) {
            if (tid == 0) atomicAdd(f0x + (t * 16 + i) * 8 + j, 1);
        } else if (role == 2) {
            if (tid == 0) { atomicAdd(f1x + (t * 16 + i) * 8 + j, 1);
                            atomicAdd(cnt1x + t * 16 + i, 1); }
        } else {
            // ---- pointwise LSTM cell (gate order i,f,g,o) ----
            if (tid < 200) {
                int b = tid / 25, hc = tid % 25;
                const float* gb = gates + b * 100;
                float ig = gb[hc], fg = gb[25 + hc], gg = gb[50 + hc], og = gb[75 + hc];
                // sanitizers: residual bugs become finite + localizable
                ig = (ig == ig) ? ig : 0.f;  fg = (fg == fg) ? fg : 0.f;
                gg = (gg == gg) ? gg : 0.f;  og = (og == og) ? og : 0.f;
                ig = 1.f / (1.f + __expf(-ig));
                fg = 1.f / (1.f + __expf(-fg));
                og = 1.f / (1.f + __expf(-og));
                gg = tanhf(gg);
                cReg = fg * cReg + ig * gg;
                float h = og * tanhf(cReg);
                int bb = b0 + b, hcg = hc0 + hc;
                if (role == 1) {
                    y0ring[((t & 7) * B_ + bb) * H_ + hcg] = f2bf(h);
                    hbuf0[(t & 1) * B_ * H_ + bb * H_ + hcg] = h;
                } else {
                    y1buf[((size_t)t * B_ + bb) * H_ + hcg] = f2bf(h);
                    hbuf1[(t & 1) * B_ * H_ + bb * H_ + hcg] = h;
                }
                if (t == T_ - 1) {
                    const size_t base = (size_t)T_ * B_ * IN_;
                    const int L = (role == 1) ? 0 : 1;
                    const size_t o1 = base + (size_t)L * B_ * H_ + (size_t)bb * H_ + hcg;
                    const size_t o2 = base + 2 * (size_t)B_ * H_ + (size_t)L * B_ * H_
                                    + (size_t)bb * H_ + hcg;
                    if (isf32) { ((float*)out)[o1] = h; ((float*)out)[o2] = cReg; }
                    else       { ((u16*)out)[o1] = f2bf(h); ((u16*)out)[o2] = f2bf(cReg); }
                }
            }
            __threadfence();
            __syncthreads();
            if (tid == 0)
                atomicAdd(((role == 1) ? cnt0h : cnt1h) + t * 16 + i, 1);
        }
    }
}

// out[m][c] = sum_k y1[m][k] * fcW[c][k] + fcb[c];  m in [0, T*B)
__launch_bounds__(256)
__global__ void fc_kernel(const u16* __restrict__ y1, const u16* __restrict__ cbf,
                          const int* __restrict__ flag, void* __restrict__ out)
{
    __shared__ float y1s[16 * 201];
    const int isf32 = *flag;
    const u16* fcW = cbf + 563200;
    const u16* fcb = cbf + 583200;
    const int tid = threadIdx.x;
    const int m0 = blockIdx.x * 16;
    for (int idx = tid; idx < 16 * 200; idx += 256) {
        int r = idx / 200, k = idx % 200;
        y1s[r * 201 + k] = bf2f(y1[(size_t)(m0 + r) * 200 + k]);
    }
    __syncthreads();
    const int r = tid & 15, ct = tid >> 4;
    float acc[7] = {0.f, 0.f, 0.f, 0.f, 0.f, 0.f, 0.f};
    for (int k = 0; k < 200; ++k) {
        const float x = y1s[r * 201 + k];
        #pragma unroll
        for (int qn = 0; qn < 7; ++qn) {
            int c = ct + 16 * qn;
            if (c < 100) acc[qn] = fmaf(x, bf2f(fcW[c * 200 + k]), acc[qn]);
        }
    }
    #pragma unroll
    for (int qn = 0; qn < 7; ++qn) {
        int c = ct + 16 * qn;
        if (c < 100) {
            float v = acc[qn] + bf2f(fcb[c]);
            v = (v == v) ? v : 0.f;          // sanitizer
            const size_t oi = (size_t)(m0 + r) * 100 + c;
            if (isf32) ((float*)out)[oi] = v;
            else       ((u16*)out)[oi] = f2bf(v);
        }
    }
}

extern "C" void kernel_launch(void* const* d_in, const int* in_sizes, int n_in,
                              void* d_out, int out_size, void* d_ws, size_t ws_size,
                              hipStream_t stream)
{
    const void* inp  = d_in[0];
    const void* h0   = d_in[1];
    const void* c0   = d_in[2];
    const void* Wih0 = d_in[3];
    const void* Whh0 = d_in[4];
    const void* bih0 = d_in[5];
    const void* bhh0 = d_in[6];
    const void* Wih1 = d_in[7];
    const void* Whh1 = d_in[8];
    const void* bih1 = d_in[9];
    const void* bhh1 = d_in[10];
    const void* fcW  = d_in[11];
    const void* fcb  = d_in[12];

    // workspace layout (bytes)
    char* ws = (char*)d_ws;
    const size_t y1_off   = 0;                 // bf16 [1024][128][200]  52,428,800
    const size_t y0r_off  = 52428800;          // bf16 [8][128][200]        409,600
    const size_t pr0_off  = 52838400;          // f32  [8][128][800]      3,276,800
    const size_t pr1_off  = 56115200;          // f32  [8][128][800]      3,276,800
    const size_t hb0_off  = 59392000;          // f32  [2][128][200]        204,800
    const size_t hb1_off  = 59596800;          // f32  [2][128][200]        204,800
    const size_t f0x_off  = 59801600;          // int  [1024][16][8]        524,288
    const size_t f1x_off  = 60325888;          // int  [1024][16][8]        524,288
    const size_t c0h_off  = 60850176;          // int  [1024][16]            65,536
    const size_t c1x_off  = 60915712;          // int  [1024][16]            65,536
    const size_t c1h_off  = 60981248;          // int  [1024][16]            65,536
    const size_t cbf_off  = 61046784;          // u16  canonical [583300]  1,166,656
    const size_t ch0_off  = 62213440;          // f32  [2][128][200]         204,800
    const size_t cc0_off  = 62418240;          // f32  [2][128][200]         204,800
    const size_t flg_off  = 62623040;          // int                             64
    const size_t needed   = 62623104;
    if (ws_size < needed) return;              // fail visibly rather than corrupt

    u16*   y1buf  = (u16*)(ws + y1_off);
    u16*   y0ring = (u16*)(ws + y0r_off);
    float* pr0    = (float*)(ws + pr0_off);
    float* pr1    = (float*)(ws + pr1_off);
    float* hbuf0  = (float*)(ws + hb0_off);
    float* hbuf1  = (float*)(ws + hb1_off);
    int*   f0x    = (int*)(ws + f0x_off);
    int*   f1x    = (int*)(ws + f1x_off);
    int*   cnt0h  = (int*)(ws + c0h_off);
    int*   cnt1x  = (int*)(ws + c1x_off);
    int*   cnt1h  = (int*)(ws + c1h_off);
    u16*   cbf    = (u16*)(ws + cbf_off);
    float* ch0    = (float*)(ws + ch0_off);
    float* cc0    = (float*)(ws + cc0_off);
    int*   flag   = (int*)(ws + flg_off);

    // zero entire workspace: counters start 0; any residual staleness is finite
    hipMemsetAsync(ws, 0, needed, stream);

    detect_kernel<<<1, 256, 0, stream>>>(Wih0, flag);
    prep_kernel<<<512, 256, 0, stream>>>(Wih0, Whh0, bih0, bhh0,
                                         Wih1, Whh1, bih1, bhh1,
                                         fcW, fcb, h0, c0, cbf, ch0, cc0, flag);
    lstm_pipe<<<512, 256, 0, stream>>>(inp, cbf, ch0, cc0,
                                       y1buf, y0ring, pr0, pr1, hbuf0, hbuf1,
                                       f0x, f1x, cnt0h, cnt1x, cnt1h, flag, d_out);
    fc_kernel<<<8192, 256, 0, stream>>>(y1buf, cbf, flag, d_out);
}

// Round 5
// 12875.911 us; speedup vs baseline: 7.1007x; 7.1007x over previous
//
#include <hip/hip_runtime.h>
#include <stdint.h>

#define T_ 1024
#define B_ 128
#define IN_ 100
#define H_ 200

typedef unsigned short u16;

__device__ __forceinline__ float bf2f(u16 u) {
    union { uint32_t i; float f; } v; v.i = ((uint32_t)u) << 16; return v.f;
}
__device__ __forceinline__ u16 f2bf(float f) {
    union { uint32_t i; float f; } v; v.f = f;
    uint32_t x = v.i;
    x += 0x7fff + ((x >> 16) & 1);   // round-to-nearest-even
    return (u16)(x >> 16);
}

// fine-grained coherent (IC-level) data movement: no L2-wide fence ops
__device__ __forceinline__ void agst(float* p, float v) {
    __hip_atomic_store(p, v, __ATOMIC_RELAXED, __HIP_MEMORY_SCOPE_AGENT);
}
__device__ __forceinline__ float agld(const float* p) {
    return __hip_atomic_load((float*)p, __ATOMIC_RELAXED, __HIP_MEMORY_SCOPE_AGENT);
}

// relaxed spin (sc1 load each poll, hits Infinity Cache; no invalidates)
__device__ __forceinline__ void spin_ge(int* p, int val, int* budget) {
    while (__hip_atomic_load(p, __ATOMIC_RELAXED, __HIP_MEMORY_SCOPE_AGENT) < val) {
        __builtin_amdgcn_s_sleep(1);
        if (--(*budget) < 0) return;   // hang safety -> finite garbage, not hang
    }
}

// ---------- dtype detector: are the raw inputs f32 or bf16? ----------
__global__ void detect_kernel(const void* w, int* flag) {
    __shared__ int cnt;
    if (threadIdx.x == 0) cnt = 0;
    __syncthreads();
    const u16* p = (const u16*)w;
    int bad = 0;
    for (int e = 0; e < 16; ++e) {
        u16 u = p[threadIdx.x * 16 + e];
        int ex = (u >> 7) & 0xFF;
        float v = bf2f(u);
        float av = v < 0.f ? -v : v;
        if (ex == 0xFF || av > 0.5f) bad++;
    }
    atomicAdd(&cnt, bad);
    __syncthreads();
    if (threadIdx.x == 0) flag[0] = (cnt > 64) ? 1 : 0;
}

// ---------- canonicalize params: weights/biases/fc -> bf16, h0/c0 -> f32 ----
// canonical u16 layout (element offsets):
//   Wih0@0[80000] Whh0@80000[160000] bih0@240000[800] bhh0@240800[800]
//   Wih1@241600[160000] Whh1@401600[160000] bih1@561600[800] bhh1@562400[800]
//   fcW@563200[20000] fcb@583200[100]          (total 583300)
__global__ void prep_kernel(const void* Wih0, const void* Whh0,
                            const void* bih0, const void* bhh0,
                            const void* Wih1, const void* Whh1,
                            const void* bih1, const void* bhh1,
                            const void* fcW,  const void* fcb,
                            const void* h0,   const void* c0,
                            u16* cbf, float* ch0, float* cc0, const int* flag)
{
    const int isf32 = *flag;
    const int N = 685700;
    for (int idx = blockIdx.x * 256 + threadIdx.x; idx < N; idx += gridDim.x * 256) {
        const void* src; int e = idx; u16* du = nullptr; float* df = nullptr;
        if (e < 80000)                 { src = Wih0; du = cbf; }
        else if ((e -= 80000) < 160000){ src = Whh0; du = cbf + 80000; }
        else if ((e -= 160000) < 800)  { src = bih0; du = cbf + 240000; }
        else if ((e -= 800) < 800)     { src = bhh0; du = cbf + 240800; }
        else if ((e -= 800) < 160000)  { src = Wih1; du = cbf + 241600; }
        else if ((e -= 160000) < 160000){ src = Whh1; du = cbf + 401600; }
        else if ((e -= 160000) < 800)  { src = bih1; du = cbf + 561600; }
        else if ((e -= 800) < 800)     { src = bhh1; du = cbf + 562400; }
        else if ((e -= 800) < 20000)   { src = fcW;  du = cbf + 563200; }
        else if ((e -= 20000) < 100)   { src = fcb;  du = cbf + 583200; }
        else if ((e -= 100) < 51200)   { src = h0;   df = ch0; }
        else         { e -= 51200;       src = c0;   df = cc0; }
        float v = isf32 ? ((const float*)src)[e] : bf2f(((const u16*)src)[e]);
        if (du) du[e] = f2bf(v); else df[e] = v;
    }
}

// 512 blocks x 256 threads, 2 blocks/CU (LDS 57.6KB), all co-resident.
// Decomposition: role (4) x j (8 col-slices of 25) x i (16 batch-slices of 8).
//   role0: L0 x-half  role1: L0 h-half+cell  role2: L1 x-half  role3: L1 h-half+cell
// x-halves run ahead through depth-8 rings; h-halves carry the recurrence.
// ALL cross-block data moves through sc1 (agent-scope relaxed) atomics; flags
// are relaxed fetch_adds after __syncthreads (whose vmcnt(0) drain is the
// release). No __threadfence => no L2 writeback/invalidate storms.
__launch_bounds__(256, 2)
__global__ void lstm_pipe(const void* __restrict__ inp,
                          const u16* __restrict__ cbf,
                          const float* __restrict__ ch0, const float* __restrict__ cc0,
                          u16* y1buf, float* y0ring, float* pr0, float* pr1,
                          float* hbuf0, float* hbuf1,
                          int* f0x, int* f1x, int* cnt0h, int* cnt1x, int* cnt1h,
                          const int* __restrict__ flag, void* __restrict__ out)
{
    __shared__ __align__(16) float smem[14400];   // 57,600 B

    const int isf32 = *flag;
    const int tid = threadIdx.x;
    const int bid = blockIdx.x;
    const int q   = bid >> 3;
    const int role= q & 3;
    const int r2  = q >> 2;
    const int ih  = r2 & 1;
    const int j   = r2 >> 1;                // 0..7  (25-col slice)
    const int i   = (ih << 3) | (bid & 7);  // 0..15 (8-row batch slice)
    const int b0  = i * 8;
    const int hc0 = j * 25;
    const int Kx  = (role == 0) ? 100 : 200;

    // LDS layout (floats)
    u16* Wb = (u16*)smem;                   // [Kx][100] bf16, k-major
    float *xh, *part, *bias = nullptr, *gates = nullptr;
    if (role == 0) { xh = smem + 5000;  part = smem + 6000;  bias = smem + 7600; }
    else           { xh = smem + 10000; part = smem + 12000;
                     if (role == 2) bias = smem + 13600; else gates = smem + 13600; }

    // ---- load canonical weight slice (bf16, k-major) + bias ----
    {
        const u16* Wsrc = (role == 0) ? cbf : (role == 1) ? cbf + 80000
                        : (role == 2) ? cbf + 241600 : cbf + 401600;
        const int ldw = (role == 0) ? IN_ : H_;
        for (int idx = tid; idx < Kx * 100; idx += 256) {
            int k = idx / 100, r = idx % 100;
            int R = (r / 25) * 200 + hc0 + (r % 25);   // r = gate*25 + col
            Wb[k * 100 + r] = Wsrc[R * ldw + k];
        }
        if ((role == 0 || role == 2) && tid < 100) {
            int R = (tid / 25) * 200 + hc0 + (tid % 25);
            bias[tid] = (role == 0) ? (bf2f(cbf[240000 + R]) + bf2f(cbf[240800 + R]))
                                    : (bf2f(cbf[561600 + R]) + bf2f(cbf[562400 + R]));
        }
    }
    float cReg = 0.f;                       // c-state register (h-half roles)
    if ((role == 1 || role == 3) && tid < 200) {
        int b = tid / 25, hc = tid % 25;
        cReg = cc0[((role == 3) ? 1 : 0) * B_ * H_ + (b0 + b) * H_ + hc0 + hc];
    }
    __syncthreads();

    // GEMM mapping: w<25 -> 4 cols, bg -> 2 batch rows, kp -> K/2 chunk
    const int w  = tid & 31;
    const int qq = tid >> 5;
    const int bg = qq & 3;
    const int kp = qq >> 2;
    const int r4 = w * 4;
    const int chunk = Kx / 2;               // 50 or 100

    int budget = 2000000;

    for (int t = 0; t < T_; ++t) {
        // ---- dependency + ring-space spins ----
        if (role == 0) {
            if (t >= 8) spin_ge(cnt0h + (t - 8) * 16 + i, 8, &budget);
        } else if (role == 1) {
            spin_ge(f0x + (t * 16 + i) * 8 + j, 1, &budget);
            if (t > 0)  spin_ge(cnt0h + (t - 1) * 16 + i, 8, &budget);
            if (t >= 8) spin_ge(cnt1x + (t - 8) * 16 + i, 8, &budget);
        } else if (role == 2) {
            spin_ge(cnt0h + t * 16 + i, 8, &budget);
            if (t >= 8) spin_ge(cnt1h + (t - 8) * 16 + i, 8, &budget);
        } else {
            spin_ge(f1x + (t * 16 + i) * 8 + j, 1, &budget);
            if (t > 0) spin_ge(cnt1h + (t - 1) * 16 + i, 8, &budget);
        }
        __syncthreads();

        // ---- stage x or h into LDS: xh[k*10 + b], f32 ----
        if (role == 0) {
            for (int idx = tid; idx < 800; idx += 256) {
                int k = idx % 100, b = idx / 100;
                const size_t gi = (size_t)(t * B_ + b0 + b) * IN_ + k;
                xh[k * 10 + b] = isf32 ? ((const float*)inp)[gi]
                                       : bf2f(((const u16*)inp)[gi]);
            }
        } else if (role == 1) {
            for (int idx = tid; idx < 1600; idx += 256) {
                int k = idx % 200, b = idx / 200;
                xh[k * 10 + b] = (t == 0) ? ch0[(b0 + b) * H_ + k]
                    : agld(hbuf0 + ((t - 1) & 1) * B_ * H_ + (b0 + b) * H_ + k);
            }
        } else if (role == 2) {
            for (int idx = tid; idx < 1600; idx += 256) {
                int k = idx % 200, b = idx / 200;
                xh[k * 10 + b] = agld(y0ring + ((t & 7) * B_ + b0 + b) * H_ + k);
            }
        } else {
            for (int idx = tid; idx < 1600; idx += 256) {
                int k = idx % 200, b = idx / 200;
                xh[k * 10 + b] = (t == 0) ? ch0[B_ * H_ + (b0 + b) * H_ + k]
                    : agld(hbuf1 + ((t - 1) & 1) * B_ * H_ + (b0 + b) * H_ + k);
            }
        }
        __syncthreads();

        // ---- GEMM: 4 cols x 2 batch rows x K/2 per thread ----
        if (w < 25) {
            float4 aA = {0,0,0,0}, aB = {0,0,0,0};
            const u16*   wp = Wb + kp * chunk * 100 + r4;
            const float* xp = xh + kp * chunk * 10 + 2 * bg;
            for (int kk = 0; kk < chunk; ++kk) {
                const ushort4 wu = *(const ushort4*)wp;
                const float w0 = bf2f(wu.x), w1 = bf2f(wu.y),
                            w2 = bf2f(wu.z), w3 = bf2f(wu.w);
                const float x0 = xp[0], x1 = xp[1];
                aA.x = fmaf(w0, x0, aA.x); aA.y = fmaf(w1, x0, aA.y);
                aA.z = fmaf(w2, x0, aA.z); aA.w = fmaf(w3, x0, aA.w);
                aB.x = fmaf(w0, x1, aB.x); aB.y = fmaf(w1, x1, aB.y);
                aB.z = fmaf(w2, x1, aB.z); aB.w = fmaf(w3, x1, aB.w);
                wp += 100; xp += 10;
            }
            float* pp = part + ((kp * 4 + bg) * 25 + w) * 8;
            *(float4*)pp       = aA;
            *(float4*)(pp + 4) = aB;
        }
        __syncthreads();

        // ---- reduce k-chunks; x-halves emit partials, h-halves form gates ----
        if (tid < 200) {
            int b = tid / 25, w2 = tid % 25, bgr = b >> 1, bsr = b & 1;
            const float4 p0 = *(const float4*)(part + ((0 + bgr) * 25 + w2) * 8 + bsr * 4);
            const float4 p1 = *(const float4*)(part + ((4 + bgr) * 25 + w2) * 8 + bsr * 4);
            float4 s = { p0.x + p1.x, p0.y + p1.y, p0.z + p1.z, p0.w + p1.w };
            const int r4r = w2 * 4;
            const size_t roff = ((size_t)(t & 7) * B_ + b0 + b) * 800 + j * 100 + r4r;
            if (role == 0 || role == 2) {
                const float4 bv = *(const float4*)(bias + r4r);
                float* ring = ((role == 0) ? pr0 : pr1) + roff;
                agst(ring + 0, s.x + bv.x); agst(ring + 1, s.y + bv.y);
                agst(ring + 2, s.z + bv.z); agst(ring + 3, s.w + bv.w);
            } else {
                const float* ring = ((role == 1) ? pr0 : pr1) + roff;
                float* gp = gates + b * 100 + r4r;
                gp[0] = s.x + agld(ring + 0); gp[1] = s.y + agld(ring + 1);
                gp[2] = s.z + agld(ring + 2); gp[3] = s.w + agld(ring + 3);
            }
        }
        __syncthreads();   // per-wave vmcnt(0) drain before barrier = release

        if (role == 0) {
            if (tid == 0)
                __hip_atomic_fetch_add(f0x + (t * 16 + i) * 8 + j, 1,
                                       __ATOMIC_RELAXED, __HIP_MEMORY_SCOPE_AGENT);
        } else if (role == 2) {
            if (tid == 0) {
                __hip_atomic_fetch_add(f1x + (t * 16 + i) * 8 + j, 1,
                                       __ATOMIC_RELAXED, __HIP_MEMORY_SCOPE_AGENT);
                __hip_atomic_fetch_add(cnt1x + t * 16 + i, 1,
                                       __ATOMIC_RELAXED, __HIP_MEMORY_SCOPE_AGENT);
            }
        } else {
            // ---- pointwise LSTM cell (gate order i,f,g,o) ----
            if (tid < 200) {
                int b = tid / 25, hc = tid % 25;
                const float* gb = gates + b * 100;
                float ig = gb[hc], fg = gb[25 + hc], gg = gb[50 + hc], og = gb[75 + hc];
                ig = (ig == ig) ? ig : 0.f;  fg = (fg == fg) ? fg : 0.f;
                gg = (gg == gg) ? gg : 0.f;  og = (og == og) ? og : 0.f;
                ig = 1.f / (1.f + __expf(-ig));
                fg = 1.f / (1.f + __expf(-fg));
                og = 1.f / (1.f + __expf(-og));
                gg = tanhf(gg);
                cReg = fg * cReg + ig * gg;
                float h = og * tanhf(cReg);
                int bb = b0 + b, hcg = hc0 + hc;
                if (role == 1) {
                    agst(y0ring + ((t & 7) * B_ + bb) * H_ + hcg, h);
                    agst(hbuf0 + (t & 1) * B_ * H_ + bb * H_ + hcg, h);
                } else {
                    y1buf[((size_t)t * B_ + bb) * H_ + hcg] = f2bf(h);
                    agst(hbuf1 + (t & 1) * B_ * H_ + bb * H_ + hcg, h);
                }
                if (t == T_ - 1) {
                    const size_t base = (size_t)T_ * B_ * IN_;
                    const int L = (role == 1) ? 0 : 1;
                    const size_t o1 = base + (size_t)L * B_ * H_ + (size_t)bb * H_ + hcg;
                    const size_t o2 = base + 2 * (size_t)B_ * H_ + (size_t)L * B_ * H_
                                    + (size_t)bb * H_ + hcg;
                    if (isf32) { ((float*)out)[o1] = h; ((float*)out)[o2] = cReg; }
                    else       { ((u16*)out)[o1] = f2bf(h); ((u16*)out)[o2] = f2bf(cReg); }
                }
            }
            __syncthreads();   // drain stores (vmcnt(0) per wave) = release
            if (tid == 0)
                __hip_atomic_fetch_add(((role == 1) ? cnt0h : cnt1h) + t * 16 + i, 1,
                                       __ATOMIC_RELAXED, __HIP_MEMORY_SCOPE_AGENT);
        }
    }
}

// out[m][c] = sum_k y1[m][k] * fcW[c][k] + fcb[c];  m in [0, T*B)
__launch_bounds__(256)
__global__ void fc_kernel(const u16* __restrict__ y1, const u16* __restrict__ cbf,
                          const int* __restrict__ flag, void* __restrict__ out)
{
    __shared__ float y1s[16 * 201];
    const int isf32 = *flag;
    const u16* fcW = cbf + 563200;
    const u16* fcb = cbf + 583200;
    const int tid = threadIdx.x;
    const int m0 = blockIdx.x * 16;
    for (int idx = tid; idx < 16 * 200; idx += 256) {
        int r = idx / 200, k = idx % 200;
        y1s[r * 201 + k] = bf2f(y1[(size_t)(m0 + r) * 200 + k]);
    }
    __syncthreads();
    const int r = tid & 15, ct = tid >> 4;
    float acc[7] = {0.f, 0.f, 0.f, 0.f, 0.f, 0.f, 0.f};
    for (int k = 0; k < 200; ++k) {
        const float x = y1s[r * 201 + k];
        #pragma unroll
        for (int qn = 0; qn < 7; ++qn) {
            int c = ct + 16 * qn;
            if (c < 100) acc[qn] = fmaf(x, bf2f(fcW[c * 200 + k]), acc[qn]);
        }
    }
    #pragma unroll
    for (int qn = 0; qn < 7; ++qn) {
        int c = ct + 16 * qn;
        if (c < 100) {
            float v = acc[qn] + bf2f(fcb[c]);
            v = (v == v) ? v : 0.f;          // sanitizer
            const size_t oi = (size_t)(m0 + r) * 100 + c;
            if (isf32) ((float*)out)[oi] = v;
            else       ((u16*)out)[oi] = f2bf(v);
        }
    }
}

extern "C" void kernel_launch(void* const* d_in, const int* in_sizes, int n_in,
                              void* d_out, int out_size, void* d_ws, size_t ws_size,
                              hipStream_t stream)
{
    const void* inp  = d_in[0];
    const void* h0   = d_in[1];
    const void* c0   = d_in[2];
    const void* Wih0 = d_in[3];
    const void* Whh0 = d_in[4];
    const void* bih0 = d_in[5];
    const void* bhh0 = d_in[6];
    const void* Wih1 = d_in[7];
    const void* Whh1 = d_in[8];
    const void* bih1 = d_in[9];
    const void* bhh1 = d_in[10];
    const void* fcW  = d_in[11];
    const void* fcb  = d_in[12];

    // workspace layout (bytes)
    char* ws = (char*)d_ws;
    const size_t y1_off   = 0;                 // bf16 [1024][128][200]  52,428,800
    const size_t y0r_off  = 52428800;          // f32  [8][128][200]        819,200
    const size_t pr0_off  = 53248000;          // f32  [8][128][800]      3,276,800
    const size_t pr1_off  = 56524800;          // f32  [8][128][800]      3,276,800
    const size_t hb0_off  = 59801600;          // f32  [2][128][200]        204,800
    const size_t hb1_off  = 60006400;          // f32  [2][128][200]        204,800
    const size_t f0x_off  = 60211200;          // int  [1024][16][8]        524,288
    const size_t f1x_off  = 60735488;          // int  [1024][16][8]        524,288
    const size_t c0h_off  = 61259776;          // int  [1024][16]            65,536
    const size_t c1x_off  = 61325312;          // int  [1024][16]            65,536
    const size_t c1h_off  = 61390848;          // int  [1024][16]            65,536
    const size_t cbf_off  = 61456384;          // u16  canonical [583300]  1,166,656
    const size_t ch0_off  = 62623040;          // f32  [2][128][200]         204,800
    const size_t cc0_off  = 62827840;          // f32  [2][128][200]         204,800
    const size_t flg_off  = 63032640;          // int                             64
    const size_t needed   = 63032704;
    if (ws_size < needed) return;              // fail visibly rather than corrupt

    u16*   y1buf  = (u16*)(ws + y1_off);
    float* y0ring = (float*)(ws + y0r_off);
    float* pr0    = (float*)(ws + pr0_off);
    float* pr1    = (float*)(ws + pr1_off);
    float* hbuf0  = (float*)(ws + hb0_off);
    float* hbuf1  = (float*)(ws + hb1_off);
    int*   f0x    = (int*)(ws + f0x_off);
    int*   f1x    = (int*)(ws + f1x_off);
    int*   cnt0h  = (int*)(ws + c0h_off);
    int*   cnt1x  = (int*)(ws + c1x_off);
    int*   cnt1h  = (int*)(ws + c1h_off);
    u16*   cbf    = (u16*)(ws + cbf_off);
    float* ch0    = (float*)(ws + ch0_off);
    float* cc0    = (float*)(ws + cc0_off);
    int*   flag   = (int*)(ws + flg_off);

    // zero entire workspace: counters start 0; any residual staleness is finite
    hipMemsetAsync(ws, 0, needed, stream);

    detect_kernel<<<1, 256, 0, stream>>>(Wih0, flag);
    prep_kernel<<<512, 256, 0, stream>>>(Wih0, Whh0, bih0, bhh0,
                                         Wih1, Whh1, bih1, bhh1,
                                         fcW, fcb, h0, c0, cbf, ch0, cc0, flag);
    lstm_pipe<<<512, 256, 0, stream>>>(inp, cbf, ch0, cc0,
                                       y1buf, y0ring, pr0, pr1, hbuf0, hbuf1,
                                       f0x, f1x, cnt0h, cnt1x, cnt1h, flag, d_out);
    fc_kernel<<<8192, 256, 0, stream>>>(y1buf, cbf, flag, d_out);
}